// Round 4
// baseline (178.716 us; speedup 1.0000x reference)
//
#include <hip/hip_runtime.h>
#include <stdint.h>

#define NN 100000
#define DF 128
#define KN 15
#define LN_EPS 1e-5f

typedef __attribute__((ext_vector_type(8))) short bf16x8;
typedef __attribute__((ext_vector_type(4))) float f32x4;

static __device__ __forceinline__ unsigned short f2bf(float f) {
    union { float f; uint32_t u; } v; v.f = f;
    uint32_t r = v.u + 0x7FFFu + ((v.u >> 16) & 1u);   // RNE
    return (unsigned short)(r >> 16);
}
static __device__ __forceinline__ float uasf(uint32_t u) {
    union { uint32_t u; float f; } v; v.u = u; return v.f;
}
static __device__ __forceinline__ uint4 pack8(const float* a) {
    uint4 pk;
    pk.x = (uint)f2bf(a[0]) | ((uint)f2bf(a[1]) << 16);
    pk.y = (uint)f2bf(a[2]) | ((uint)f2bf(a[3]) << 16);
    pk.z = (uint)f2bf(a[4]) | ((uint)f2bf(a[5]) << 16);
    pk.w = (uint)f2bf(a[6]) | ((uint)f2bf(a[7]) << 16);
    return pk;
}

// ---------------- K1: fp32 -> bf16 tables (nf, and W) ----------------
// grid = 6250 (+8 for W). 8 floats per thread.
template<int DOW>
__global__ __launch_bounds__(256)
void conv_kernel(const float* __restrict__ nf, const float* __restrict__ W,
                 uint4* __restrict__ tbl, uint4* __restrict__ wb)
{
    int b = blockIdx.x;
    const float* src; uint4* dst; int i;
    if (DOW && b >= 6250) { i = (b - 6250) * 256 + threadIdx.x; src = W; dst = wb; }
    else                  { i = b * 256 + threadIdx.x;          src = nf; dst = tbl; }
    const float4* p = (const float4*)src + (size_t)i * 2;
    float4 a = p[0], c = p[1];
    float v[8] = {a.x, a.y, a.z, a.w, c.x, c.y, c.z, c.w};
    dst[i] = pack8(v);
}

// ---------------- K2: gather-mean -> agg (bf16 rows) ----------------
// One 16-lane group per node; 15 slot loads independent & predicated;
// no reduce, no LDS, no barrier. grid = NN/16 = 6250.
__global__ __launch_bounds__(256, 6)
void gather_kernel(const uint4* __restrict__ tbl, const int* __restrict__ nbr,
                   const int* __restrict__ cnts, uint4* __restrict__ agg)
{
    const int tid  = threadIdx.x;
    const int s    = tid & 15;
    const int node = blockIdx.x * 16 + (tid >> 4);
    const int cnt  = cnts[node];
    int idxreg = (s < KN) ? nbr[(size_t)node * KN + s] : 0;

    float acc[8] = {0.f,0.f,0.f,0.f,0.f,0.f,0.f,0.f};
    #pragma unroll
    for (int st = 0; st < KN; ++st) {
        int idx = __shfl(idxreg, st, 16);
        if (st < cnt) {
            uint4 r = tbl[(size_t)idx * 16 + s];
            acc[0] += uasf(r.x << 16); acc[1] += uasf(r.x & 0xffff0000u);
            acc[2] += uasf(r.y << 16); acc[3] += uasf(r.y & 0xffff0000u);
            acc[4] += uasf(r.z << 16); acc[5] += uasf(r.z & 0xffff0000u);
            acc[6] += uasf(r.w << 16); acc[7] += uasf(r.w & 0xffff0000u);
        }
    }
    float inv = 1.0f / (float)(cnt > 0 ? cnt : 1);
    float v[8];
    #pragma unroll
    for (int j = 0; j < 8; ++j) v[j] = acc[j] * inv;
    agg[(size_t)node * 16 + s] = pack8(v);
}

// ---------------- K3: MFMA linear + residual + LN + ReLU + where ----------------
// Zero LDS: A-fragments direct from global agg; B-fragments direct from global
// bf16 W (32KB, L1-resident). 256 thr = 4 waves, 64 nodes/block.
__global__ __launch_bounds__(256, 4)
void gemm_kernel(const uint4* __restrict__ agg, const uint4* __restrict__ wb,
                 const float* __restrict__ nf, const int* __restrict__ cnts,
                 const float* __restrict__ bias, const float* __restrict__ lnw,
                 const float* __restrict__ lnb, float* __restrict__ out)
{
    const int tid  = threadIdx.x;
    const int lane = tid & 63;
    const int w    = tid >> 6;
    const int l15  = lane & 15;
    const int q    = lane >> 4;
    const int base = blockIdx.x * 64;

    int mrow = base + w * 16 + l15;
    if (mrow >= NN) mrow = NN - 1;

    bf16x8 afr[4];
    #pragma unroll
    for (int kk = 0; kk < 4; ++kk)
        afr[kk] = ((const bf16x8*)agg)[(size_t)mrow * 16 + kk * 4 + q];

    f32x4 acc[8];
    #pragma unroll
    for (int nb = 0; nb < 8; ++nb) acc[nb] = (f32x4){0.f,0.f,0.f,0.f};

    #pragma unroll
    for (int nb = 0; nb < 8; ++nb) {
        int n = nb * 16 + l15;
        #pragma unroll
        for (int kk = 0; kk < 4; ++kk) {
            bf16x8 bfr = ((const bf16x8*)wb)[n * 16 + kk * 4 + q];
            acc[nb] = __builtin_amdgcn_mfma_f32_16x16x32_bf16(afr[kk], bfr, acc[nb], 0, 0, 0);
        }
    }

    float bv[8], lwv[8], lbv[8];
    #pragma unroll
    for (int nb = 0; nb < 8; ++nb) {
        int c = nb * 16 + l15;
        bv[nb]  = bias[c];
        lwv[nb] = lnw[c];
        lbv[nb] = lnb[c];
    }

    #pragma unroll
    for (int r = 0; r < 4; ++r) {
        int node = base + w * 16 + q * 4 + r;     // C/D row = (lane>>4)*4 + reg
        if (node < NN) {
            int cnt = cnts[node];
            float vals[8], nfv[8];
            float s = 0.f, sq = 0.f;
            #pragma unroll
            for (int nb = 0; nb < 8; ++nb) {
                int c = nb * 16 + l15;
                float nv = nf[(size_t)node * DF + c];
                float comb = nv + acc[nb][r] + bv[nb];
                nfv[nb]  = nv;
                vals[nb] = comb;
                s  += comb;
                sq += comb * comb;
            }
            #pragma unroll
            for (int off = 1; off < 16; off <<= 1) {
                s  += __shfl_xor(s,  off);
                sq += __shfl_xor(sq, off);
            }
            float mu   = s  * (1.0f / 128.0f);
            float var  = sq * (1.0f / 128.0f) - mu * mu;
            float rstd = rsqrtf(var + LN_EPS);
            #pragma unroll
            for (int nb = 0; nb < 8; ++nb) {
                int c = nb * 16 + l15;
                float nrm = (vals[nb] - mu) * rstd * lwv[nb] + lbv[nb];
                float rel = fmaxf(nrm, 0.0f);
                out[(size_t)node * DF + c] = (cnt > 0) ? rel : nfv[nb];
            }
        }
    }
}

// ---------------- Fallback: proven fused fp32 kernel (round-2) ----------------
__global__ __launch_bounds__(512, 4)
void fused_kernel(const float* __restrict__ nf, const int* __restrict__ nbr,
                  const int* __restrict__ cnts, const float* __restrict__ W,
                  const float* __restrict__ bias, const float* __restrict__ lnw,
                  const float* __restrict__ lnb, float* __restrict__ out)
{
    __shared__ __align__(16) unsigned char WbS[32768];
    __shared__ __align__(16) unsigned char AtS[32768];
    __shared__ int idxS[128 * 16];
    __shared__ int cntS[128];

    const int tid  = threadIdx.x;
    const int lane = tid & 63;
    const int w    = tid >> 6;
    const int base = blockIdx.x * 128;

    {
        const float4* W4 = (const float4*)W;
        #pragma unroll
        for (int it = 0; it < 8; ++it) {
            int e = it * 2048 + tid * 4;
            float4 v = W4[e >> 2];
            int n = e >> 7, k = e & 127;
            ushort4 h;
            h.x = f2bf(v.x); h.y = f2bf(v.y); h.z = f2bf(v.z); h.w = f2bf(v.w);
            *(ushort4*)(WbS + ((n * 256 + k * 2) ^ ((n & 7) << 4))) = h;
        }
    }
    {
        if (lane < 16) {
            int m = w * 16 + lane;
            int node = base + m;
            cntS[m] = (node < NN) ? cnts[node] : 0;
        }
        #pragma unroll
        for (int it = 0; it < 4; ++it) {
            int e = it * 64 + lane;
            if (e < 240) {
                int mm = e / 15, kk = e - mm * 15;
                int m = w * 16 + mm;
                int node = base + m;
                idxS[m * 16 + kk] = (node < NN) ? nbr[(size_t)node * KN + kk] : 0;
            }
        }
    }
    {
        const int g = lane >> 4;
        const int s = lane & 15;
        #pragma unroll 2
        for (int t = 0; t < 16; ++t) {
            int m = w * 16 + t;
            int cnt = cntS[m];
            float acc[8] = {0.f,0.f,0.f,0.f,0.f,0.f,0.f,0.f};
            #pragma unroll
            for (int st = 0; st < 4; ++st) {
                int k = st * 4 + g;
                int idx = idxS[m * 16 + (k & 15)];
                if (k < cnt) {
                    const float4* p = (const float4*)(nf + (size_t)idx * DF + s * 8);
                    float4 u0 = p[0];
                    float4 u1 = p[1];
                    acc[0]+=u0.x; acc[1]+=u0.y; acc[2]+=u0.z; acc[3]+=u0.w;
                    acc[4]+=u1.x; acc[5]+=u1.y; acc[6]+=u1.z; acc[7]+=u1.w;
                }
            }
            #pragma unroll
            for (int j = 0; j < 8; ++j) {
                acc[j] += __shfl_xor(acc[j], 16);
                acc[j] += __shfl_xor(acc[j], 32);
            }
            if (g == 0) {
                float inv = 1.0f / (float)(cnt > 0 ? cnt : 1);
                float v[8];
                #pragma unroll
                for (int j = 0; j < 8; ++j) v[j] = acc[j] * inv;
                *(uint4*)(AtS + ((m * 256 + s * 16) ^ ((m & 7) << 4))) = pack8(v);
            }
        }
    }
    __syncthreads();

    const int l15 = lane & 15;
    const int q   = lane >> 4;
    bf16x8 afr[4];
    #pragma unroll
    for (int kk = 0; kk < 4; ++kk) {
        int m = w * 16 + l15;
        afr[kk] = *(const bf16x8*)(AtS + ((m * 256 + kk * 64 + q * 16) ^ ((m & 7) << 4)));
    }
    f32x4 acc[8];
    #pragma unroll
    for (int nb = 0; nb < 8; ++nb) acc[nb] = (f32x4){0.f,0.f,0.f,0.f};
    #pragma unroll
    for (int nb = 0; nb < 8; ++nb) {
        #pragma unroll
        for (int kk = 0; kk < 4; ++kk) {
            int n = nb * 16 + l15;
            bf16x8 bfr = *(const bf16x8*)(WbS + ((n * 256 + kk * 64 + q * 16) ^ ((n & 7) << 4)));
            acc[nb] = __builtin_amdgcn_mfma_f32_16x16x32_bf16(afr[kk], bfr, acc[nb], 0, 0, 0);
        }
    }
    float bv[8], lwv[8], lbv[8];
    #pragma unroll
    for (int nb = 0; nb < 8; ++nb) {
        int c = nb * 16 + l15;
        bv[nb]  = bias[c];
        lwv[nb] = lnw[c];
        lbv[nb] = lnb[c];
    }
    #pragma unroll
    for (int r = 0; r < 4; ++r) {
        int m = w * 16 + q * 4 + r;
        int node = base + m;
        if (node < NN) {
            int cnt = cntS[m];
            float vals[8], nfv[8];
            float s = 0.f, sq = 0.f;
            #pragma unroll
            for (int nb = 0; nb < 8; ++nb) {
                int c = nb * 16 + l15;
                float nv = nf[(size_t)node * DF + c];
                float comb = nv + acc[nb][r] + bv[nb];
                nfv[nb]  = nv;
                vals[nb] = comb;
                s  += comb;
                sq += comb * comb;
            }
            #pragma unroll
            for (int off = 1; off < 16; off <<= 1) {
                s  += __shfl_xor(s,  off);
                sq += __shfl_xor(sq, off);
            }
            float mu   = s  * (1.0f / 128.0f);
            float var  = sq * (1.0f / 128.0f) - mu * mu;
            float rstd = rsqrtf(var + LN_EPS);
            #pragma unroll
            for (int nb = 0; nb < 8; ++nb) {
                int c = nb * 16 + l15;
                float nrm = (vals[nb] - mu) * rstd * lwv[nb] + lbv[nb];
                float rel = fmaxf(nrm, 0.0f);
                out[(size_t)node * DF + c] = (cnt > 0) ? rel : nfv[nb];
            }
        }
    }
}

extern "C" void kernel_launch(void* const* d_in, const int* in_sizes, int n_in,
                              void* d_out, int out_size, void* d_ws, size_t ws_size,
                              hipStream_t stream) {
    const float* nf   = (const float*)d_in[0];
    const int*   nbr  = (const int*)d_in[1];
    const int*   cnts = (const int*)d_in[2];
    const float* W    = (const float*)d_in[3];
    const float* b    = (const float*)d_in[4];
    const float* lnw  = (const float*)d_in[5];
    const float* lnb  = (const float*)d_in[6];
    float* out = (float*)d_out;

    const size_t tblB = (size_t)NN * 256;        // 25.6 MB bf16 node table
    const size_t aggB = (size_t)NN * 256;        // 25.6 MB bf16 agg rows
    const size_t wbB  = 32768;                   // 32 KB bf16 W

    if (ws_size >= tblB + aggB + wbB) {
        uint4* tbl = (uint4*)d_ws;
        uint4* agg = (uint4*)((char*)d_ws + tblB);
        uint4* wb  = (uint4*)((char*)d_ws + tblB + aggB);
        conv_kernel<1><<<6258, 256, 0, stream>>>(nf, W, tbl, wb);
        gather_kernel<<<NN / 16, 256, 0, stream>>>(tbl, nbr, cnts, agg);
        gemm_kernel<<<(NN + 63) / 64, 256, 0, stream>>>(agg, wb, nf, cnts, b, lnw, lnb, out);
    } else {
        fused_kernel<<<(NN + 127) / 128, 512, 0, stream>>>(nf, nbr, cnts, W, b, lnw, lnb, out);
    }
}